// Round 2
// baseline (579.393 us; speedup 1.0000x reference)
//
#include <hip/hip_runtime.h>
#include <stdint.h>
#include <math.h>

// Problem dims
#define BS_  256
#define NSEQ 128
#define HH   512
#define DD   1152      // 2H + Z
#define VV   32000
#define BN_  (BS_*NSEQ)  // 32768

typedef float  f32x4  __attribute__((ext_vector_type(4)));
typedef __bf16 bf16x8 __attribute__((ext_vector_type(8)));

__device__ __forceinline__ f32x4 mfma16(bf16x8 a, bf16x8 b, f32x4 c) {
    return __builtin_amdgcn_mfma_f32_16x16x32_bf16(a, b, c, 0, 0, 0);
}

__device__ __forceinline__ bf16x8 pack8(f32x4 a, f32x4 b) {
    bf16x8 v;
    v[0] = (__bf16)a[0]; v[1] = (__bf16)a[1]; v[2] = (__bf16)a[2]; v[3] = (__bf16)a[3];
    v[4] = (__bf16)b[0]; v[5] = (__bf16)b[1]; v[6] = (__bf16)b[2]; v[7] = (__bf16)b[3];
    return v;
}

__device__ __forceinline__ float tanh_fast(float x) {
    float e = __expf(2.f * x);
    return 1.f - __fdividef(2.f, e + 1.f);
}

// async global->LDS, 16B per lane. LDS dest = wave-uniform base + lane*16.
__device__ __forceinline__ void gload16(const void* g, void* l) {
    __builtin_amdgcn_global_load_lds(
        (const __attribute__((address_space(1))) void*)g,
        (__attribute__((address_space(3))) void*)l, 16, 0, 0);
}

// ---------------------------------------------------------------------------
// cast f32 -> bf16, 8 elems/thread
// ---------------------------------------------------------------------------
__global__ __launch_bounds__(256) void k_cast(const float* __restrict__ src,
                                              __bf16* __restrict__ dst, int n8)
{
    int i = blockIdx.x * 256 + threadIdx.x;
    int stride = gridDim.x * 256;
    for (; i < n8; i += stride) {
        const f32x4* s = (const f32x4*)(src + (size_t)i * 8);
        f32x4 a = s[0], b = s[1];
        *(bf16x8*)(dst + (size_t)i * 8) = pack8(a, b);
    }
}

// ---------------------------------------------------------------------------
// K2: attention logits via global_load_lds staging.
// A = enc tile (f32 in LDS, cvt after read), B = W1 (bf16 in LDS).
// 128x128 tile, BK=32, 4 waves 2x2. One barrier per K-step (m97 schedule).
// Both-sides XOR swizzle: f32 rows kc^=(row&7), bf16 rows kc^=((row>>1)&3).
// Fused tanh/vt epilogue -> u_part. grid = 2048 XCD-swizzled.
// ---------------------------------------------------------------------------
__global__ __launch_bounds__(256) void k_attn2(
    const float* __restrict__ enc_e, const float* __restrict__ enc_s,
    const __bf16* __restrict__ W1be, const __bf16* __restrict__ W1bs,
    const float* __restrict__ vte, const float* __restrict__ vts,
    const float* __restrict__ dt_e, const float* __restrict__ dt_s,
    float* __restrict__ u_part)
{
    const int L = blockIdx.x;
    const int n = (L >> 3) & 3;                  // col phase 0..3
    const int G = (L & 7) + ((L >> 5) << 3);     // 0..511
    const int e = G >> 8;
    const int b = G & 255;

    const float*  enc = e ? enc_s : enc_e;
    const __bf16* W1  = e ? W1bs : W1be;
    const float*  vt  = e ? vts : vte;
    const float*  dt  = e ? dt_s : dt_e;

    __shared__ float  lA[2][4096];   // 128x32 f32 tile per buf (16KB each)
    __shared__ __bf16 lB[2][4096];   // 128x32 bf16 tile per buf (8KB each)
    __shared__ float  upart[2][128];

    const int t = threadIdx.x;
    const int w = t >> 6, wr = w >> 1, wc = w & 1;
    const int lane = t & 63, g = lane >> 4, r = lane & 15;

    const float*  Ag = enc + (size_t)b * (128 * 512);
    const __bf16* Bg = W1 + (size_t)n * (128 * 512);

    // staging address tables (global elem offset, wave-uniform LDS elem base)
    int aoff[4], boff[2], aldsb[4], bldsb[2];
    #pragma unroll
    for (int i = 0; i < 4; ++i) {                 // A: 1024 16B-chunks (f32)
        int c = i * 256 + w * 64 + lane;
        int row = c >> 3, kc = c & 7;
        aoff[i]  = row * 512 + ((kc ^ (row & 7)) << 2);
        aldsb[i] = (i * 256 + w * 64) << 2;       // floats
    }
    #pragma unroll
    for (int i = 0; i < 2; ++i) {                 // B: 512 16B-chunks (bf16)
        int c = i * 256 + w * 64 + lane;
        int row = c >> 2, kc = c & 3;
        boff[i]  = row * 512 + ((kc ^ ((row >> 1) & 3)) << 3);
        bldsb[i] = (i * 256 + w * 64) << 3;       // bf16s
    }

    f32x4 acc[4][4];
    #pragma unroll
    for (int i = 0; i < 4; ++i)
        #pragma unroll
        for (int j = 0; j < 4; ++j) acc[i][j] = (f32x4){0.f, 0.f, 0.f, 0.f};

    // prologue stage into buf 0
    #pragma unroll
    for (int i = 0; i < 4; ++i) gload16(Ag + aoff[i], &lA[0][aldsb[i]]);
    #pragma unroll
    for (int i = 0; i < 2; ++i) gload16(Bg + boff[i], &lB[0][bldsb[i]]);

    for (int kb = 0; kb < 16; ++kb) {
        const int buf = kb & 1;
        __syncthreads();     // drains vmcnt: buf ready; all waves done reading buf^1
        if (kb + 1 < 16) {
            const int k0 = (kb + 1) * 32;
            #pragma unroll
            for (int i = 0; i < 4; ++i) gload16(Ag + aoff[i] + k0, &lA[buf ^ 1][aldsb[i]]);
            #pragma unroll
            for (int i = 0; i < 2; ++i) gload16(Bg + boff[i] + k0, &lB[buf ^ 1][bldsb[i]]);
        }
        bf16x8 af[4], bfr[4];
        #pragma unroll
        for (int j = 0; j < 4; ++j) {
            int row = wc * 64 + j * 16 + r;
            bfr[j] = *(const bf16x8*)&lB[buf][row * 32 + ((g ^ ((row >> 1) & 3)) << 3)];
        }
        #pragma unroll
        for (int i = 0; i < 4; ++i) {
            int row = wr * 64 + i * 16 + r;
            int s = row & 7;
            f32x4 a0 = *(const f32x4*)&lA[buf][row * 32 + (((g << 1) ^ s) << 2)];
            f32x4 a1 = *(const f32x4*)&lA[buf][row * 32 + ((((g << 1) | 1) ^ s) << 2)];
            af[i] = pack8(a0, a1);
        }
        #pragma unroll
        for (int i = 0; i < 4; ++i)
            #pragma unroll
            for (int j = 0; j < 4; ++j)
                acc[i][j] = mfma16(af[i], bfr[j], acc[i][j]);
    }

    // fused epilogue: partial u_row = sum over this block's 128 cols
    float dv[4], vv[4];
    #pragma unroll
    for (int j = 0; j < 4; ++j) {
        int col = n * 128 + wc * 64 + j * 16 + r;
        dv[j] = dt[(size_t)b * 512 + col];
        vv[j] = vt[col];
    }
    #pragma unroll
    for (int i = 0; i < 4; ++i) {
        #pragma unroll
        for (int q = 0; q < 4; ++q) {
            float s = 0.f;
            #pragma unroll
            for (int j = 0; j < 4; ++j)
                s += vv[j] * tanh_fast(acc[i][j][q] + dv[j]);
            #pragma unroll
            for (int m = 1; m < 16; m <<= 1) s += __shfl_xor(s, m);
            if (r == 0) upart[wc][wr * 64 + i * 16 + g * 4 + q] = s;
        }
    }
    __syncthreads();
    if (t < 128)
        u_part[((size_t)(n * 2 + e)) * BN_ + b * 128 + t] = upart[0][t] + upart[1][t];
}

// ---------------------------------------------------------------------------
// K6: vocab GEMM via global_load_lds staging.
// A = h_new (bf16 in LDS, produced by k_gru), B = Wout (f32 in LDS, cvt on read).
// Same schedule/swizzles as k_attn2. grid = 512 XCD-swizzled (p>=250 idle).
// ---------------------------------------------------------------------------
__global__ __launch_bounds__(256) void k_vocab2(
    const __bf16* __restrict__ A,   // h_new bf16 [256][1152]
    const float* __restrict__ B,    // Wout f32 [32000][1152]
    const float* __restrict__ bias, float* __restrict__ C)
{
    const int L = blockIdx.x;
    const int p  = (L & 7) + ((L >> 4) << 3);   // col tile 0..255
    const int rr = (L >> 3) & 1;                // row tile 0..1
    if (p >= 250) return;
    const int rb = rr * 128, cb = p * 128;

    __shared__ __bf16 lA[2][4096];   // 128x32 bf16
    __shared__ float  lB[2][4096];   // 128x32 f32

    const int t = threadIdx.x;
    const int w = t >> 6, wr = w >> 1, wc = w & 1;
    const int lane = t & 63, g = lane >> 4, r = lane & 15;

    const __bf16* Ag = A + (size_t)rb * DD;
    const float*  Bg = B + (size_t)cb * DD;

    int aoff[2], boff[4], aldsb[2], bldsb[4];
    #pragma unroll
    for (int i = 0; i < 2; ++i) {                 // A: 512 chunks (bf16)
        int c = i * 256 + w * 64 + lane;
        int row = c >> 2, kc = c & 3;
        aoff[i]  = row * DD + ((kc ^ ((row >> 1) & 3)) << 3);
        aldsb[i] = (i * 256 + w * 64) << 3;
    }
    #pragma unroll
    for (int i = 0; i < 4; ++i) {                 // B: 1024 chunks (f32)
        int c = i * 256 + w * 64 + lane;
        int row = c >> 3, kc = c & 7;
        boff[i]  = row * DD + ((kc ^ (row & 7)) << 2);
        bldsb[i] = (i * 256 + w * 64) << 2;
    }

    f32x4 acc[4][4];
    #pragma unroll
    for (int i = 0; i < 4; ++i)
        #pragma unroll
        for (int j = 0; j < 4; ++j) acc[i][j] = (f32x4){0.f, 0.f, 0.f, 0.f};

    #pragma unroll
    for (int i = 0; i < 2; ++i) gload16(Ag + aoff[i], &lA[0][aldsb[i]]);
    #pragma unroll
    for (int i = 0; i < 4; ++i) gload16(Bg + boff[i], &lB[0][bldsb[i]]);

    for (int kb = 0; kb < 36; ++kb) {
        const int buf = kb & 1;
        __syncthreads();
        if (kb + 1 < 36) {
            const int k0 = (kb + 1) * 32;
            #pragma unroll
            for (int i = 0; i < 2; ++i) gload16(Ag + aoff[i] + k0, &lA[buf ^ 1][aldsb[i]]);
            #pragma unroll
            for (int i = 0; i < 4; ++i) gload16(Bg + boff[i] + k0, &lB[buf ^ 1][bldsb[i]]);
        }
        bf16x8 af[4], bfr[4];
        #pragma unroll
        for (int i = 0; i < 4; ++i) {
            int row = wr * 64 + i * 16 + r;
            af[i] = *(const bf16x8*)&lA[buf][row * 32 + ((g ^ ((row >> 1) & 3)) << 3)];
        }
        #pragma unroll
        for (int j = 0; j < 4; ++j) {
            int row = wc * 64 + j * 16 + r;
            int s = row & 7;
            f32x4 b0 = *(const f32x4*)&lB[buf][row * 32 + (((g << 1) ^ s) << 2)];
            f32x4 b1 = *(const f32x4*)&lB[buf][row * 32 + ((((g << 1) | 1) ^ s) << 2)];
            bfr[j] = pack8(b0, b1);
        }
        #pragma unroll
        for (int i = 0; i < 4; ++i)
            #pragma unroll
            for (int j = 0; j < 4; ++j)
                acc[i][j] = mfma16(af[i], bfr[j], acc[i][j]);
    }

    #pragma unroll
    for (int j = 0; j < 4; ++j) {
        const int col = cb + wc * 64 + j * 16 + r;
        const float bv = bias[col];
        #pragma unroll
        for (int i = 0; i < 4; ++i) {
            #pragma unroll
            for (int q = 0; q < 4; ++q) {
                const int row = rb + wr * 64 + i * 16 + g * 4 + q;
                C[(size_t)row * VV + col] = acc[i][j][q] + bv;
            }
        }
    }
}

// ---------------------------------------------------------------------------
// 128x128-tile reg-staged GEMM core (kept for K4b).
// ---------------------------------------------------------------------------
__global__ __launch_bounds__(256) void k_tile128(
    const float* __restrict__ A, const float* __restrict__ B,
    const float* __restrict__ bias, float* __restrict__ C,
    int K, int ldc)
{
    const int rb = blockIdx.x * 128;
    const int cb = blockIdx.y * 128;
    const int t = threadIdx.x;
    const int w = t >> 6, wr = w >> 1, wc = w & 1;
    const int lane = t & 63, g = lane >> 4, r = lane & 15;
    const int s_row = t >> 1, s_h = t & 1;

    __shared__ bf16x8 sm[2][2][512];

    const float* Ap = A + (size_t)(rb + s_row) * K + s_h * 16;
    const float* Bp = B + (size_t)(cb + s_row) * K + s_h * 16;

    const int kg0 = 2 * s_h, kg1 = 2 * s_h + 1;
    const int swz0 = kg0 * 128 + ((s_row & 112) | ((s_row ^ (kg0 << 2)) & 15));
    const int swz1 = kg1 * 128 + ((s_row & 112) | ((s_row ^ (kg1 << 2)) & 15));

    int ai[4], bi[4];
    #pragma unroll
    for (int i = 0; i < 4; ++i) {
        ai[i] = g * 128 + wr * 64 + i * 16 + ((r ^ (g << 2)) & 15);
        bi[i] = g * 128 + wc * 64 + i * 16 + ((r ^ (g << 2)) & 15);
    }

    const int KS = K >> 5;
    f32x4 pa0 = ((const f32x4*)Ap)[0], pa1 = ((const f32x4*)Ap)[1],
          pa2 = ((const f32x4*)Ap)[2], pa3 = ((const f32x4*)Ap)[3];
    f32x4 pb0 = ((const f32x4*)Bp)[0], pb1 = ((const f32x4*)Bp)[1],
          pb2 = ((const f32x4*)Bp)[2], pb3 = ((const f32x4*)Bp)[3];

    f32x4 acc[4][4];
    #pragma unroll
    for (int i = 0; i < 4; ++i)
        #pragma unroll
        for (int j = 0; j < 4; ++j) acc[i][j] = (f32x4){0.f, 0.f, 0.f, 0.f};

    for (int kb = 0; kb < KS; ++kb) {
        const int buf = kb & 1;
        sm[buf][0][swz0] = pack8(pa0, pa1);
        sm[buf][0][swz1] = pack8(pa2, pa3);
        sm[buf][1][swz0] = pack8(pb0, pb1);
        sm[buf][1][swz1] = pack8(pb2, pb3);
        __syncthreads();
        if (kb + 1 < KS) {
            const float* a2 = Ap + (kb + 1) * 32;
            const float* b2 = Bp + (kb + 1) * 32;
            pa0 = ((const f32x4*)a2)[0]; pa1 = ((const f32x4*)a2)[1];
            pa2 = ((const f32x4*)a2)[2]; pa3 = ((const f32x4*)a2)[3];
            pb0 = ((const f32x4*)b2)[0]; pb1 = ((const f32x4*)b2)[1];
            pb2 = ((const f32x4*)b2)[2]; pb3 = ((const f32x4*)b2)[3];
        }
        bf16x8 af[4], bfr[4];
        #pragma unroll
        for (int i = 0; i < 4; ++i) af[i]  = sm[buf][0][ai[i]];
        #pragma unroll
        for (int j = 0; j < 4; ++j) bfr[j] = sm[buf][1][bi[j]];
        #pragma unroll
        for (int i = 0; i < 4; ++i)
            #pragma unroll
            for (int j = 0; j < 4; ++j)
                acc[i][j] = mfma16(af[i], bfr[j], acc[i][j]);
    }

    #pragma unroll
    for (int j = 0; j < 4; ++j) {
        const int col = cb + wc * 64 + j * 16 + r;
        const float bv = bias ? bias[col] : 0.f;
        #pragma unroll
        for (int i = 0; i < 4; ++i) {
            #pragma unroll
            for (int q = 0; q < 4; ++q) {
                const int row = rb + wr * 64 + i * 16 + g * 4 + q;
                C[(size_t)row * ldc + col] = acc[i][j][q] + bv;
            }
        }
    }
}

// ---------------------------------------------------------------------------
// K1: prev_h against virtual concat [W2e | W2s | w_hh], 64x64 tiles.
// ---------------------------------------------------------------------------
__global__ __launch_bounds__(256) void k_prevh(
    const float* __restrict__ prev_h, const float* __restrict__ W2e,
    const float* __restrict__ W2s, const float* __restrict__ w_hh,
    const float* __restrict__ b_hh,
    float* __restrict__ dt_e, float* __restrict__ dt_s, float* __restrict__ gh)
{
    const int cb = blockIdx.x * 64;
    const int rb = blockIdx.y * 64;
    const int t  = threadIdx.x;
    const int w = t >> 6, lane = t & 63, g = lane >> 4, r = lane & 15;
    const int s_row = t >> 2, s_kc = t & 3;
    const int K = DD;

    __shared__ bf16x8 sm[2][2][256];

    const float* Ap = prev_h + (size_t)(rb + s_row) * K + s_kc * 8;
    const float* Bp;
    {
        int brow = cb + s_row;
        if (cb < 512)        Bp = W2e + (size_t)brow * K;
        else if (cb < 1024)  Bp = W2s + (size_t)(brow - 512) * K;
        else                 Bp = w_hh + (size_t)(brow - 1024) * K;
        Bp += s_kc * 8;
    }

    const int KS = K >> 5;   // 36
    f32x4 pa0 = *(const f32x4*)Ap, pa1 = *(const f32x4*)(Ap + 4);
    f32x4 pb0 = *(const f32x4*)Bp, pb1 = *(const f32x4*)(Bp + 4);

    f32x4 acc[4] = {{0,0,0,0},{0,0,0,0},{0,0,0,0},{0,0,0,0}};

    for (int kb = 0; kb < KS; ++kb) {
        sm[kb & 1][0][s_kc * 64 + s_row] = pack8(pa0, pa1);
        sm[kb & 1][1][s_kc * 64 + s_row] = pack8(pb0, pb1);
        __syncthreads();
        if (kb + 1 < KS) {
            const float* a2 = Ap + (kb + 1) * 32;
            const float* b2 = Bp + (kb + 1) * 32;
            pa0 = *(const f32x4*)a2; pa1 = *(const f32x4*)(a2 + 4);
            pb0 = *(const f32x4*)b2; pb1 = *(const f32x4*)(b2 + 4);
        }
        bf16x8 af = sm[kb & 1][0][g * 64 + w * 16 + r];
        #pragma unroll
        for (int j = 0; j < 4; ++j) {
            bf16x8 bf = sm[kb & 1][1][g * 64 + j * 16 + r];
            acc[j] = mfma16(af, bf, acc[j]);
        }
    }

    #pragma unroll
    for (int j = 0; j < 4; ++j) {
        int col = cb + j * 16 + r;
        #pragma unroll
        for (int q = 0; q < 4; ++q) {
            int row = rb + w * 16 + g * 4 + q;
            float v = acc[j][q];
            if (cb < 512)       dt_e[(size_t)row * 512 + col] = v;
            else if (cb < 1024) dt_s[(size_t)row * 512 + (col - 512)] = v;
            else {
                int c0 = col - 1024;
                gh[(size_t)row * 3456 + c0] = v + b_hh[c0];
            }
        }
    }
}

// ---------------------------------------------------------------------------
// K3: masked softmax (summing 4 u partials), plan softmax, ctx weighted sums,
// y_ctx via atomicAdd into zeroed buffer. grid = (256, 2), 256 thr.
// ---------------------------------------------------------------------------
__global__ __launch_bounds__(256) void k_ctx(
    const float* __restrict__ u_part, const int* __restrict__ mask_e,
    const int* __restrict__ mask_s, const float* __restrict__ enc_e,
    const float* __restrict__ enc_s, const float* __restrict__ prev_h,
    const float* __restrict__ plan_W, const float* __restrict__ plan_b,
    const float* __restrict__ prev_y,
    float* __restrict__ y_ctx, float* __restrict__ plan_out)
{
    const int b = blockIdx.x;
    const int rh = blockIdx.y;
    const int t = threadIdx.x;
    const int lane = t & 63, wid = t >> 6, half = t >> 7, n = t & 127;

    __shared__ float aw[2][128];
    __shared__ float red[16];
    __shared__ float planv[2];

    const int* mask = half ? mask_s : mask_e;
    float uv = u_part[(size_t)(0 * 2 + half) * BN_ + b * 128 + n]
             + u_part[(size_t)(1 * 2 + half) * BN_ + b * 128 + n]
             + u_part[(size_t)(2 * 2 + half) * BN_ + b * 128 + n]
             + u_part[(size_t)(3 * 2 + half) * BN_ + b * 128 + n];
    bool msk = mask[b * 128 + n] != 0;
    float val = msk ? -3.4e38f : uv;

    float mx = val;
    #pragma unroll
    for (int m = 1; m < 64; m <<= 1) mx = fmaxf(mx, __shfl_xor(mx, m));
    if (lane == 0) red[wid] = mx;
    __syncthreads();
    mx = fmaxf(red[half * 2], red[half * 2 + 1]);
    float ex = msk ? 0.f : __expf(uv - mx);
    float sm = ex;
    #pragma unroll
    for (int m = 1; m < 64; m <<= 1) sm += __shfl_xor(sm, m);
    if (lane == 0) red[4 + wid] = sm;
    __syncthreads();
    sm = red[4 + half * 2] + red[4 + half * 2 + 1];
    aw[half][n] = ex / sm;

    float p0 = 0.f, p1 = 0.f;
    for (int i = t; i < DD; i += 256) {
        float hv = prev_h[(size_t)b * DD + i];
        p0 += hv * plan_W[i];
        p1 += hv * plan_W[DD + i];
    }
    #pragma unroll
    for (int m = 1; m < 64; m <<= 1) { p0 += __shfl_xor(p0, m); p1 += __shfl_xor(p1, m); }
    if (lane == 0) { red[8 + wid] = p0; red[12 + wid] = p1; }
    __syncthreads();
    if (t == 0) {
        float l0 = red[8] + red[9] + red[10] + red[11] + plan_b[0];
        float l1 = red[12] + red[13] + red[14] + red[15] + plan_b[1];
        float mm = fmaxf(l0, l1);
        float e0 = __expf(l0 - mm), e1 = __expf(l1 - mm);
        float ss = e0 + e1;
        planv[0] = e0 / ss; planv[1] = e1 / ss;
        if (rh == 0) {
            plan_out[b * 2 + 0] = planv[0];
            plan_out[b * 2 + 1] = planv[1];
        }
    }
    __syncthreads();

    const int ee = t >> 7;
    const int tt = t & 127;
    const float pl = planv[ee];
    const float* base = (ee ? enc_s : enc_e) + (size_t)b * 65536 + (size_t)(rh * 64) * 512 + tt * 4;
    f32x4 accv = {0.f, 0.f, 0.f, 0.f};
    #pragma unroll 4
    for (int row = 0; row < 64; ++row) {
        f32x4 v = *(const f32x4*)(base + (size_t)row * 512);
        float a = aw[ee][rh * 64 + row];
        accv += a * v;
    }
    float* dst = y_ctx + (size_t)b * 1024 + 512 + tt * 4;
    atomicAdd(dst + 0, pl * accv[0]);
    atomicAdd(dst + 1, pl * accv[1]);
    atomicAdd(dst + 2, pl * accv[2]);
    atomicAdd(dst + 3, pl * accv[3]);

    if (rh == 0 && t < 128) {
        f32x4 v = *(const f32x4*)(prev_y + (size_t)b * 512 + t * 4);
        *(f32x4*)(y_ctx + (size_t)b * 1024 + t * 4) = v;
    }
}

// ---------------------------------------------------------------------------
// K4a: 64x64-tile GEMM (small x = y_ctx@Wc^T)
// ---------------------------------------------------------------------------
__global__ __launch_bounds__(256) void k_gemm_bias(
    const float* __restrict__ A, const float* __restrict__ B,
    const float* __restrict__ bias, float* __restrict__ C,
    int K, int ldc)
{
    const int cb = blockIdx.x * 64;
    const int rb = blockIdx.y * 64;
    const int t  = threadIdx.x;
    const int w = t >> 6, lane = t & 63, g = lane >> 4, r = lane & 15;
    const int s_row = t >> 2, s_kc = t & 3;

    __shared__ bf16x8 sm[2][2][256];

    const float* Ap = A + (size_t)(rb + s_row) * K + s_kc * 8;
    const float* Bp = B + (size_t)(cb + s_row) * K + s_kc * 8;

    const int KS = K >> 5;
    f32x4 pa0 = *(const f32x4*)Ap, pa1 = *(const f32x4*)(Ap + 4);
    f32x4 pb0 = *(const f32x4*)Bp, pb1 = *(const f32x4*)(Bp + 4);

    f32x4 acc[4] = {{0,0,0,0},{0,0,0,0},{0,0,0,0},{0,0,0,0}};

    for (int kb = 0; kb < KS; ++kb) {
        sm[kb & 1][0][s_kc * 64 + s_row] = pack8(pa0, pa1);
        sm[kb & 1][1][s_kc * 64 + s_row] = pack8(pb0, pb1);
        __syncthreads();
        if (kb + 1 < KS) {
            const float* a2 = Ap + (kb + 1) * 32;
            const float* b2 = Bp + (kb + 1) * 32;
            pa0 = *(const f32x4*)a2; pa1 = *(const f32x4*)(a2 + 4);
            pb0 = *(const f32x4*)b2; pb1 = *(const f32x4*)(b2 + 4);
        }
        bf16x8 af = sm[kb & 1][0][g * 64 + w * 16 + r];
        #pragma unroll
        for (int j = 0; j < 4; ++j) {
            bf16x8 bf = sm[kb & 1][1][g * 64 + j * 16 + r];
            acc[j] = mfma16(af, bf, acc[j]);
        }
    }
    #pragma unroll
    for (int j = 0; j < 4; ++j) {
        int col = cb + j * 16 + r;
        float bv = bias ? bias[col] : 0.f;
        #pragma unroll
        for (int q = 0; q < 4; ++q) {
            int row = rb + w * 16 + g * 4 + q;
            C[(size_t)row * ldc + col] = acc[j][q] + bv;
        }
    }
}

// ---------------------------------------------------------------------------
// K5: GRU gates + bf16 copy of h_new for vocab GEMM. grid=(3, BS), 384 thr.
// ---------------------------------------------------------------------------
__global__ __launch_bounds__(384) void k_gru(
    const float* __restrict__ gx, const float* __restrict__ gh,
    const float* __restrict__ prev_h, float* __restrict__ h_new,
    float* __restrict__ out_hidden, __bf16* __restrict__ h_new_bf)
{
    int d = blockIdx.x * 384 + threadIdx.x;   // 0..1151
    int b = blockIdx.y;
    size_t o3 = (size_t)b * 3456;
    float xr = gx[o3 + d], xz = gx[o3 + 1152 + d], xn = gx[o3 + 2304 + d];
    float hr = gh[o3 + d], hz = gh[o3 + 1152 + d], hn = gh[o3 + 2304 + d];
    float rr = 1.f / (1.f + __expf(-(xr + hr)));
    float zz = 1.f / (1.f + __expf(-(xz + hz)));
    float nv = tanhf(xn + rr * hn);
    float hv = (1.f - zz) * nv + zz * prev_h[(size_t)b * DD + d];
    h_new[(size_t)b * DD + d] = hv;
    out_hidden[(size_t)b * DD + d] = hv;
    h_new_bf[(size_t)b * DD + d] = (__bf16)hv;
}

// ---------------------------------------------------------------------------
extern "C" void kernel_launch(void* const* d_in, const int* in_sizes, int n_in,
                              void* d_out, int out_size, void* d_ws, size_t ws_size,
                              hipStream_t stream)
{
    const float* prev_y = (const float*)d_in[0];
    const float* prev_h = (const float*)d_in[1];
    const float* enc_e  = (const float*)d_in[2];
    const float* enc_s  = (const float*)d_in[3];
    const int*   mask_e = (const int*)d_in[5];
    const int*   mask_s = (const int*)d_in[6];
    const float* W1e    = (const float*)d_in[7];
    const float* W2e    = (const float*)d_in[8];
    const float* vte    = (const float*)d_in[9];
    const float* W1s    = (const float*)d_in[10];
    const float* W2s    = (const float*)d_in[11];
    const float* vts    = (const float*)d_in[12];
    const float* plan_W = (const float*)d_in[13];
    const float* plan_b = (const float*)d_in[14];
    const float* Wc     = (const float*)d_in[15];
    const float* bc     = (const float*)d_in[16];
    const float* w_ih   = (const float*)d_in[17];
    const float* w_hh   = (const float*)d_in[18];
    const float* b_ih   = (const float*)d_in[19];
    const float* b_hh   = (const float*)d_in[20];
    const float* Wout   = (const float*)d_in[21];
    const float* bout   = (const float*)d_in[22];

    float* out = (float*)d_out;
    float* ws  = (float*)d_ws;

    // workspace layout (lifetime-based aliasing):
    float* gh     = ws;                    // 884736   (K1 -> K5)
    float* big2   = ws + 884736;           // 884736:  dt_e|dt_s (K1->K2) then gx (K4b->K5)
    float* upxx   = big2 + 884736;         // 262144:  u_part (K2->K3) then xx (K4a->K4b)
    float* y_ctx  = upxx + 262144;         // 262144   (K3 -> K4a)
    float* h_new  = y_ctx + 262144;        // 294912   (K5, f32 copy)
    // bf16 region after f32 region:
    __bf16* W1be  = (__bf16*)(h_new + 294912);       // 262144 bf16
    __bf16* W1bs  = W1be + 262144;                   // 262144 bf16
    __bf16* hnbf  = W1bs + 262144;                   // 294912 bf16

    float* dt_e  = big2;
    float* dt_s  = big2 + 131072;
    float* gx    = big2;
    float* u_part = upxx;
    float* xx    = upxx;

    float* dec_out  = out;                 // 256*32000
    float* dec_hid  = out + 8192000;       // 256*1152
    float* plan_out = out + 8486912;       // 256*2

    // zero y_ctx (ctx accumulated via atomics)
    hipMemsetAsync(y_ctx, 0, 262144 * sizeof(float), stream);

    // W1 casts (tiny, no deps)
    k_cast<<<dim3(128), 256, 0, stream>>>(W1e, W1be, 32768);
    k_cast<<<dim3(128), 256, 0, stream>>>(W1s, W1bs, 32768);

    // K1: dt_e, dt_s, gh
    k_prevh<<<dim3(70, 4), 256, 0, stream>>>(prev_h, W2e, W2s, w_hh, b_hh,
                                             dt_e, dt_s, gh);

    // K2: attention logit partials (2048 XCD-swizzled blocks, gload_lds core)
    k_attn2<<<dim3(2048), 256, 0, stream>>>(
        enc_e, enc_s, W1be, W1bs, vte, vts, dt_e, dt_s, u_part);

    // K3: softmax + ctx + plan + y_ctx
    k_ctx<<<dim3(BS_, 2), 256, 0, stream>>>(u_part, mask_e, mask_s, enc_e, enc_s,
                                            prev_h, plan_W, plan_b, prev_y,
                                            y_ctx, plan_out);

    // K4a: x = y_ctx @ Wc^T + bc
    k_gemm_bias<<<dim3(8, 4), 256, 0, stream>>>(y_ctx, Wc, bc, xx, 1024, 512);
    // K4b: gx = x @ w_ih^T + b_ih
    k_tile128<<<dim3(2, 27), 256, 0, stream>>>(xx, w_ih, b_ih, gx, 512, 3456);

    // K5: GRU (+ bf16 h_new)
    k_gru<<<dim3(3, BS_), 384, 0, stream>>>(gx, gh, prev_h, h_new, dec_hid, hnbf);

    // K6: dec_output = h_new @ Wout^T + bout (gload_lds core, f32 Wout in LDS)
    k_vocab2<<<dim3(512), 256, 0, stream>>>(hnbf, Wout, bout, dec_out);
}